// Round 5
// baseline (577.226 us; speedup 1.0000x reference)
//
#include <hip/hip_runtime.h>
#include <cstdint>
#include <cstddef>
#include <cmath>

#define BS 64
#define SEQ 1024
#define IN_DIM 512
#define EMB 1024
#define HID 512
#define KSEL 306
#define MROWS (BS * KSEL)  // 19584 = 153 * 128

typedef __bf16 bf16_t;
typedef bf16_t bf16x8 __attribute__((ext_vector_type(8)));
typedef bf16_t bf16x4 __attribute__((ext_vector_type(4)));
typedef float f32x4 __attribute__((ext_vector_type(4)));

__device__ __forceinline__ void async16(const void* g, void* l) {
  __builtin_amdgcn_global_load_lds(
      (const __attribute__((address_space(1))) unsigned int*)g,
      (__attribute__((address_space(3))) unsigned int*)l, 16, 0, 0);
}

// float atomic max via signed-max / unsigned-min trick (no NaNs present).
__device__ __forceinline__ void atomicMaxF(float* a, float v) {
  if (v >= 0.f)
    atomicMax((int*)a, __float_as_int(v));
  else
    atomicMin((unsigned int*)a, __float_as_uint(v));
}

// ---------- meta: eos position per batch; init out to -inf ----------
__global__ void k_meta(const int* __restrict__ text, int* __restrict__ eos,
                       float* __restrict__ out) {
  int b = blockIdx.x;
  __shared__ int cnt;
  if (threadIdx.x == 0) cnt = 0;
  __syncthreads();
  int local = 0;
  for (int i = threadIdx.x; i < SEQ; i += blockDim.x)
    local += (text[b * SEQ + i] != 0) ? 1 : 0;
  atomicAdd(&cnt, local);
  for (int c = threadIdx.x; c < EMB; c += blockDim.x)
    out[(b << 10) + c] = -INFINITY;
  __syncthreads();
  if (threadIdx.x == 0) {
    int L = cnt > 1 ? cnt : 1;
    int e = L - 1;
    if (e > SEQ - 1) e = SEQ - 1;
    eos[b] = e;
  }
}

// ---------- column exp-sum partials (softmax denominator), no atomics ----------
// grid (BS, 16); thread covers 4 adjacent columns, wave covers a full row (4KB).
__global__ void k_colsum(const float* __restrict__ atten, float* __restrict__ part) {
  int b = blockIdx.x;
  int r0 = blockIdx.y << 6;
  int c = threadIdx.x << 2;
  const float* base = atten + ((size_t)b << 20) + ((size_t)r0 << 10) + c;
  float4 s = {0.f, 0.f, 0.f, 0.f};
#pragma unroll 4
  for (int r = 0; r < 64; ++r) {
    float4 x = *(const float4*)(base + ((size_t)r << 10));
    s.x += __expf((isfinite(x.x) ? x.x : 0.f) - 12.f);
    s.y += __expf((isfinite(x.y) ? x.y : 0.f) - 12.f);
    s.z += __expf((isfinite(x.z) ? x.z : 0.f) - 12.f);
    s.w += __expf((isfinite(x.w) ? x.w : 0.f) - 12.f);
  }
  *(float4*)&part[((((size_t)blockIdx.y << 6) | b) << 10) | c] = s;
}

// ---------- selected (eos-row) softmax value per column, with masking ----------
__global__ void k_selval(const float* __restrict__ atten, const int* __restrict__ text,
                         const int* __restrict__ eos, const float* __restrict__ part,
                         float* __restrict__ selval) {
  int b = blockIdx.x >> 2;
  int c = ((blockIdx.x & 3) << 8) | threadIdx.x;
  int e = eos[b];
  float cs = 0.f;
#pragma unroll
  for (int p = 0; p < 16; ++p) cs += part[(((p << 6) | b) << 10) | c];
  float v = atten[((size_t)b << 20) + ((size_t)e << 10) + c];
  if (!isfinite(v)) v = 0.f;
  int tok = text[(b << 10) | c];
  float res;
  if (tok == 0) res = 0.f;
  else if (c == 0 || c == e) res = 1.f / 1024.f;  // fully-masked column -> uniform
  else res = __expf(v - 12.f) / cs;
  selval[(b << 10) | c] = res;
}

// ---------- top-K by rank counting (tie-break: lower index wins) ----------
// grid (BS, 4) x 256 threads: 4x the CU coverage vs one block per batch.
__global__ void k_topk(const float* __restrict__ selval, int* __restrict__ selidx) {
  int b = blockIdx.x;
  int i = (blockIdx.y << 8) | threadIdx.x;
  __shared__ float vals[SEQ];
  for (int j = threadIdx.x; j < SEQ; j += 256) vals[j] = selval[(b << 10) + j];
  __syncthreads();
  float vc = vals[i];
  int rank = 0;
  for (int j = 0; j < SEQ; ++j) {
    float vj = vals[j];
    rank += (vj > vc || (vj == vc && j < i)) ? 1 : 0;
  }
  if (rank < KSEL) selidx[b * KSEL + rank] = i;
}

// ---------- gather selected rows + L2 normalize -> bf16 into xcat[:, 0:512] ----------
__global__ void k_gather(const float* __restrict__ features, const int* __restrict__ sel,
                         bf16_t* __restrict__ xcat) {
  int row = blockIdx.x;  // 0..MROWS-1
  int b = row / KSEL;
  int k = row - b * KSEL;
  int idx = sel[b * KSEL + k];
  const float4* src = (const float4*)(features + (((size_t)b << 10) + idx) * IN_DIM);
  float4 v = src[threadIdx.x];  // 128 threads * float4 = 512
  float ss = v.x * v.x + v.y * v.y + v.z * v.z + v.w * v.w;
#pragma unroll
  for (int off = 32; off > 0; off >>= 1) ss += __shfl_down(ss, off, 64);
  __shared__ float wsum[2];
  int lane = threadIdx.x & 63, wid = threadIdx.x >> 6;
  if (lane == 0) wsum[wid] = ss;
  __syncthreads();
  float total = wsum[0] + wsum[1];
  float scale = 1.f / fmaxf(sqrtf(total), 1e-6f);
  bf16x4 o;
  o[0] = (bf16_t)(v.x * scale);
  o[1] = (bf16_t)(v.y * scale);
  o[2] = (bf16_t)(v.z * scale);
  o[3] = (bf16_t)(v.w * scale);
  *(bf16x4*)(xcat + (size_t)row * EMB + (threadIdx.x << 2)) = o;
}

// ---------- tiled transpose + f32->bf16: dst[n][k] = src[k][n] ----------
__global__ void k_transpose_bf16(const float* __restrict__ src, int srcld,
                                 bf16_t* __restrict__ dst, int dstld) {
  __shared__ float tile[32][33];
  int k0 = blockIdx.x << 5, n0 = blockIdx.y << 5;
  int tx = threadIdx.x, ty = threadIdx.y;
#pragma unroll
  for (int i = 0; i < 4; i++)
    tile[ty + 8 * i][tx] = src[(size_t)(k0 + ty + 8 * i) * srcld + n0 + tx];
  __syncthreads();
#pragma unroll
  for (int i = 0; i < 4; i++)
    dst[(size_t)(n0 + ty + 8 * i) * dstld + k0 + tx] = (bf16_t)tile[tx][ty + 8 * i];
}

// ---------- bf16 MFMA GEMM: 128x128 tile, 4 waves, 16x16x32 MFMA ----------
// XCD-aware bijective swizzle: same-A-panel blocks land consecutively on one XCD
// so the A panel is fetched past L2 once instead of gridDim.y times.
// MODE 0: C(bf16) = A*Bt^T + bias, plus BN column sum/sumsq atomics into stats.
// MODE 1: no C write; v = A*Bt^T + bias; per-batch column max atomics into outmax.
template <int MODE>
__global__ __launch_bounds__(256, 2) void k_mfma_gemm(
    const bf16_t* __restrict__ A, int lda, const bf16_t* __restrict__ Bt, int ldb,
    const float* __restrict__ bias, bf16_t* __restrict__ C, int ldc, int K,
    float* __restrict__ stats, float* __restrict__ outmax) {
  __shared__ __align__(16) bf16_t As[128 * 32];
  __shared__ __align__(16) bf16_t Bs[128 * 32];
  int tid = threadIdx.x;

  // --- bijective chunked XCD swizzle (m204 form), n-fastest decode ---
  int MT = gridDim.x, NT = gridDim.y;
  int nwg = MT * NT;
  int flat = blockIdx.y * MT + blockIdx.x;          // hw linear dispatch id
  int q = nwg >> 3, r = nwg & 7;
  int xcd = flat & 7, ii = flat >> 3;
  int lin = (xcd < r ? xcd * (q + 1) : r * (q + 1) + (xcd - r) * q) + ii;
  int mtile = lin / NT;
  int ntile = lin - mtile * NT;
  int m0 = mtile << 7, n0 = ntile << 7;

  int wave = tid >> 6, lane = tid & 63;
  int wm = (wave >> 1) << 6, wn = (wave & 1) << 6;
  int lrow = lane & 15, quad = lane >> 4;

  f32x4 acc[4][4];
#pragma unroll
  for (int i = 0; i < 4; i++)
#pragma unroll
    for (int j = 0; j < 4; j++) acc[i][j] = (f32x4){0.f, 0.f, 0.f, 0.f};

  // staging: chunk c covers 16B; row = c>>2, kcol = (c&3)*8
  int c0 = tid, c1 = 256 + tid;
  int ar0 = c0 >> 2, ak0 = (c0 & 3) << 3;
  int ar1 = c1 >> 2, ak1 = (c1 & 3) << 3;
  const bf16_t* Ap0 = A + (size_t)(m0 + ar0) * lda + ak0;
  const bf16_t* Ap1 = A + (size_t)(m0 + ar1) * lda + ak1;
  const bf16_t* Bp0 = Bt + (size_t)(n0 + ar0) * ldb + ak0;
  const bf16_t* Bp1 = Bt + (size_t)(n0 + ar1) * ldb + ak1;

  for (int k0 = 0; k0 < K; k0 += 32) {
    async16(Ap0 + k0, &As[c0 << 3]);
    async16(Ap1 + k0, &As[c1 << 3]);
    async16(Bp0 + k0, &Bs[c0 << 3]);
    async16(Bp1 + k0, &Bs[c1 << 3]);
    __syncthreads();

    bf16x8 af[4], bfr[4];
#pragma unroll
    for (int i = 0; i < 4; i++)
      af[i] = *(const bf16x8*)&As[((wm + (i << 4) + lrow) << 5) + (quad << 3)];
#pragma unroll
    for (int j = 0; j < 4; j++)
      bfr[j] = *(const bf16x8*)&Bs[((wn + (j << 4) + lrow) << 5) + (quad << 3)];
#pragma unroll
    for (int i = 0; i < 4; i++)
#pragma unroll
      for (int j = 0; j < 4; j++)
        acc[i][j] = __builtin_amdgcn_mfma_f32_16x16x32_bf16(af[i], bfr[j], acc[i][j], 0, 0, 0);
    __syncthreads();
  }

  // C/D layout: col = lane&15, row = quad*4 + reg
  if (MODE == 0) {
#pragma unroll
    for (int j = 0; j < 4; j++) {
      int n = n0 + wn + (j << 4) + lrow;
      float bv = bias[n];
      float s = 0.f, qq = 0.f;
#pragma unroll
      for (int i = 0; i < 4; i++) {
        int mbase = m0 + wm + (i << 4) + (quad << 2);
#pragma unroll
        for (int rr = 0; rr < 4; rr++) {
          float v = acc[i][j][rr] + bv;
          C[(size_t)(mbase + rr) * ldc + n] = (bf16_t)v;
          s += v;
          qq += v * v;
        }
      }
      s += __shfl_xor(s, 16, 64);
      s += __shfl_xor(s, 32, 64);
      qq += __shfl_xor(qq, 16, 64);
      qq += __shfl_xor(qq, 32, 64);
      if (quad == 0) {
        atomicAdd(&stats[n], s);
        atomicAdd(&stats[HID + n], qq);
      }
    }
  } else {
    int mw = m0 + wm;          // wave covers rows mw .. mw+63
    int b0w = mw / KSEL;       // tile spans <= 2 batches (64 < 306)
    int cut = (b0w + 1) * KSEL;
#pragma unroll
    for (int j = 0; j < 4; j++) {
      int n = n0 + wn + (j << 4) + lrow;
      float bv = bias[n];
      float mx0 = -INFINITY, mx1 = -INFINITY;
#pragma unroll
      for (int i = 0; i < 4; i++) {
#pragma unroll
        for (int rr = 0; rr < 4; rr++) {
          int m = mw + (i << 4) + (quad << 2) + rr;
          float v = acc[i][j][rr] + bv;
          if (m < cut) mx0 = fmaxf(mx0, v);
          else mx1 = fmaxf(mx1, v);
        }
      }
      mx0 = fmaxf(mx0, __shfl_xor(mx0, 16, 64));
      mx0 = fmaxf(mx0, __shfl_xor(mx0, 32, 64));
      mx1 = fmaxf(mx1, __shfl_xor(mx1, 16, 64));
      mx1 = fmaxf(mx1, __shfl_xor(mx1, 32, 64));
      if (quad == 0) {
        atomicMaxF(&outmax[(b0w << 10) + n], mx0);
        if (cut < mw + 64) atomicMaxF(&outmax[((b0w + 1) << 10) + n], mx1);
      }
    }
  }
}

// BN params + fused bias for GEMM2 (merged, one launch of EMB threads).
__global__ void k_bnparam(const float* __restrict__ stats, const float* __restrict__ g,
                          const float* __restrict__ be, float* __restrict__ scsh,
                          const float* __restrict__ lin_b, const float* __restrict__ b2,
                          float* __restrict__ biasC) {
  int c = threadIdx.x;  // EMB threads
  biasC[c] = lin_b[c] + b2[c];
  if (c < HID) {
    float inv = 1.f / (float)MROWS;
    float mu = stats[c] * inv;
    float var = stats[HID + c] * inv - mu * mu;  // biased var
    var = fmaxf(var, 0.f);
    float sc = g[c] * rsqrtf(var + 1e-5f);
    scsh[c] = sc;
    scsh[HID + c] = fmaf(-mu, sc, be[c]);
  }
}

// BN apply + ReLU on bf16 h, emit bf16 into xcat[:, 512:1024]
__global__ void k_bnapply(const bf16_t* __restrict__ h, const float* __restrict__ scsh,
                          bf16_t* __restrict__ xcat) {
  size_t idx = (size_t)blockIdx.x * blockDim.x + threadIdx.x;  // over MROWS*64
  bf16x8 x = ((const bf16x8*)h)[idx];
  int c = (int)(idx & 63) << 3;
  size_t row = idx >> 6;
  bf16x8 o;
#pragma unroll
  for (int t = 0; t < 8; ++t) {
    float v = (float)x[t];
    float a = fmaxf(fmaf(v, scsh[c + t], scsh[HID + c + t]), 0.f);
    o[t] = (bf16_t)a;
  }
  *(bf16x8*)(xcat + row * EMB + 512 + c) = o;
}

extern "C" void kernel_launch(void* const* d_in, const int* in_sizes, int n_in,
                              void* d_out, int out_size, void* d_ws, size_t ws_size,
                              hipStream_t stream) {
  const float* features = (const float*)d_in[0];
  const float* atten    = (const float*)d_in[1];
  const int*   text     = (const int*)d_in[2];
  const float* lin_w    = (const float*)d_in[3];
  const float* lin_b    = (const float*)d_in[4];
  const float* w1       = (const float*)d_in[5];
  const float* b1       = (const float*)d_in[6];
  const float* g1       = (const float*)d_in[7];
  const float* be1      = (const float*)d_in[8];
  const float* w2       = (const float*)d_in[9];
  const float* b2       = (const float*)d_in[10];
  float* out = (float*)d_out;

  char* ws = (char*)d_ws;
  int*    eos    = (int*)(ws + 0);               // 64 int
  float*  stats  = (float*)(ws + 256);           // 1024 f32
  float*  scsh   = (float*)(ws + 4608);          // 1024 f32
  float*  biasC  = (float*)(ws + 8704);          // 1024 f32
  float*  part   = (float*)(ws + 12800);         // 16*64*1024 f32 (4 MB)
  float*  selval = (float*)(ws + 4207104UL);     // 64*1024 f32
  int*    selidx = (int*)(ws + 4469248UL);       // 64*306 int
  bf16_t* w1t    = (bf16_t*)(ws + 4547584UL);    // 512*512 bf16
  bf16_t* wcatt  = (bf16_t*)(ws + 5071872UL);    // 1024*1024 bf16
  bf16_t* xcat   = (bf16_t*)(ws + 7169024UL);    // 19584*1024 bf16 (40 MB)
  bf16_t* h      = (bf16_t*)(ws + 47277056UL);   // 19584*512 bf16 (20 MB)

  hipMemsetAsync(stats, 0, 4096, stream);

  k_meta<<<BS, 256, 0, stream>>>(text, eos, out);
  k_colsum<<<dim3(BS, 16), 256, 0, stream>>>(atten, part);
  k_selval<<<BS * 4, 256, 0, stream>>>(atten, text, eos, part, selval);
  k_topk<<<dim3(BS, 4), 256, 0, stream>>>(selval, selidx);
  k_gather<<<MROWS, 128, 0, stream>>>(features, selidx, xcat);

  // weight prep (runs every call; tiny)
  k_transpose_bf16<<<dim3(16, 16), dim3(32, 8), 0, stream>>>(w1, HID, w1t, IN_DIM);
  k_transpose_bf16<<<dim3(16, 32), dim3(32, 8), 0, stream>>>(lin_w, EMB, wcatt, EMB);
  k_transpose_bf16<<<dim3(16, 32), dim3(32, 8), 0, stream>>>(w2, EMB, wcatt + 512, EMB);

  // GEMM1: h = xcat[:, :512] @ w1 + b1, fused BN stats (M=19584, N=512, K=512)
  k_mfma_gemm<0><<<dim3(MROWS / 128, HID / 128), 256, 0, stream>>>(
      xcat, EMB, w1t, IN_DIM, b1, h, HID, IN_DIM, stats, nullptr);

  k_bnparam<<<1, EMB, 0, stream>>>(stats, g1, be1, scsh, lin_b, b2, biasC);
  k_bnapply<<<(MROWS * (HID / 8)) / 256, 256, 0, stream>>>(h, scsh, xcat);

  // GEMM2: fused = [xf | relu(bn(h))] @ [lin_w ; w2] + (lin_b+b2), fused max-pool
  // (M=19584, N=1024, K=1024); no C materialization.
  k_mfma_gemm<1><<<dim3(MROWS / 128, EMB / 128), 256, 0, stream>>>(
      xcat, EMB, wcatt, EMB, biasC, nullptr, 0, EMB, nullptr, out);
}